// Round 5
// baseline (569.188 us; speedup 1.0000x reference)
//
#include <hip/hip_runtime.h>

#define BATCH   8
#define HW      (1024 * 1024)
#define NA      512
#define EPSV    1e-8f
#define LAML    0.01f
#define LAMS    0.01f

#define BPB      256                        // blocks per batch
#define NBLOCKS  (BATCH * BPB)              // 2048
#define PIXB     (HW / BPB)                 // 4096 pixels per block
#define UNROLL   4                          // float4 groups per thread

// no-return LDS atomic add, workgroup scope, relaxed — emits ds_add_f32
#define LDS_ADD(slot, val) \
    (void)__hip_atomic_fetch_add(&(slot), (val), __ATOMIC_RELAXED, __HIP_MEMORY_SCOPE_WORKGROUP)

// Pass 1 (hybrid): half the pixels accumulate via LDS atomics (DS pipe),
// half via global atomics into gsum (L2 pipe) — the two pipes run concurrently.
__global__ __launch_bounds__(256) void k_sums(const float* __restrict__ lights,
                                              const float* __restrict__ settle,
                                              const int*   __restrict__ admin,
                                              float*       __restrict__ partial,
                                              float*       __restrict__ gsum) {
    __shared__ float lsum[4][NA];           // one copy per wave
    const int tid = threadIdx.x;
    const int wid = tid >> 6;

    #pragma unroll
    for (int i = tid; i < 4 * NA; i += 256) ((float*)lsum)[i] = 0.0f;
    __syncthreads();

    const int b     = blockIdx.x >> 8;      // / BPB
    const int chunk = blockIdx.x & (BPB - 1);
    const long base = (long)b * HW + (long)chunk * PIXB;

    const float4* __restrict__ L4 = (const float4*)(lights + base);
    const float4* __restrict__ S4 = (const float4*)(settle + base);
    const int4*   __restrict__ A4 = (const int4*)(admin + base);

    float4 l[UNROLL], s[UNROLL];
    int4   a[UNROLL];
    #pragma unroll
    for (int u = 0; u < UNROLL; ++u) {
        const int v = tid + u * 256;
        l[u] = L4[v];
        s[u] = S4[v];
        a[u] = A4[v];
    }
    __builtin_amdgcn_sched_barrier(0);      // keep all 12 loads in flight

    float* gs = gsum + b * NA;
    // u = 2,3 -> global (L2) atomics, issued first so they're in flight
    #pragma unroll
    for (int u = 2; u < 4; ++u) {
        atomicAdd(&gs[a[u].x], (l[u].x + LAML) * (s[u].x + LAMS));
        atomicAdd(&gs[a[u].y], (l[u].y + LAML) * (s[u].y + LAMS));
        atomicAdd(&gs[a[u].z], (l[u].z + LAML) * (s[u].z + LAMS));
        atomicAdd(&gs[a[u].w], (l[u].w + LAML) * (s[u].w + LAMS));
    }
    // u = 0,1 -> LDS (DS pipe) atomics, grind concurrently
    float* ls = lsum[wid];
    #pragma unroll
    for (int u = 0; u < 2; ++u) {
        LDS_ADD(ls[a[u].x], (l[u].x + LAML) * (s[u].x + LAMS));
        LDS_ADD(ls[a[u].y], (l[u].y + LAML) * (s[u].y + LAMS));
        LDS_ADD(ls[a[u].z], (l[u].z + LAML) * (s[u].z + LAMS));
        LDS_ADD(ls[a[u].w], (l[u].w + LAML) * (s[u].w + LAMS));
    }
    __syncthreads();

    float* dst = partial + (long)blockIdx.x * NA;
    for (int i = tid; i < NA; i += 256)
        dst[i] = lsum[0][i] + lsum[1][i] + lsum[2][i] + lsum[3][i];
}

// Reduce 256 chunk-partials per (batch, admin), add the global-atomic part,
// emit factor = C/(S+eps).
__global__ __launch_bounds__(512) void k_reduce(const float* __restrict__ partial,
                                                const float* __restrict__ gsum,
                                                const float* __restrict__ census,
                                                float*       __restrict__ factor) {
    const int b = blockIdx.x;
    const int a = threadIdx.x;              // 512 threads = NA
    const float* p = partial + (long)b * BPB * NA + a;
    float acc = gsum[b * NA + a];
    #pragma unroll 8
    for (int c = 0; c < BPB; ++c) acc += p[(long)c * NA];
    factor[b * NA + a] = census[a] / (acc + EPSV);
}

// Pass 2: factor table per batch in LDS, recompute score, write out.
__global__ __launch_bounds__(256) void k_out(const float* __restrict__ lights,
                                             const float* __restrict__ settle,
                                             const int*   __restrict__ admin,
                                             const float* __restrict__ factor,
                                             float*       __restrict__ out) {
    __shared__ float lfac[NA];
    const int tid = threadIdx.x;

    const int b     = blockIdx.x >> 8;
    const int chunk = blockIdx.x & (BPB - 1);

    for (int i = tid; i < NA; i += 256)
        lfac[i] = factor[b * NA + i];
    __syncthreads();

    const long base = (long)b * HW + (long)chunk * PIXB;
    const float4* __restrict__ L4 = (const float4*)(lights + base);
    const float4* __restrict__ S4 = (const float4*)(settle + base);
    const int4*   __restrict__ A4 = (const int4*)(admin + base);
    float4*       __restrict__ O4 = (float4*)(out + base);

    #pragma unroll
    for (int u = 0; u < UNROLL; ++u) {
        const int v = tid + u * 256;
        float4 l = L4[v];
        float4 s = S4[v];
        int4   a = A4[v];
        float4 o;
        o.x = (l.x + LAML) * (s.x + LAMS) * lfac[a.x];
        o.y = (l.y + LAML) * (s.y + LAMS) * lfac[a.y];
        o.z = (l.z + LAML) * (s.z + LAMS) * lfac[a.z];
        o.w = (l.w + LAML) * (s.w + LAMS) * lfac[a.w];
        O4[v] = o;
    }
}

extern "C" void kernel_launch(void* const* d_in, const int* in_sizes, int n_in,
                              void* d_out, int out_size, void* d_ws, size_t ws_size,
                              hipStream_t stream) {
    const float* lights = (const float*)d_in[0];
    const float* settle = (const float*)d_in[1];
    const int*   admin  = (const int*)d_in[2];
    const float* census = (const float*)d_in[3];
    float*       out    = (float*)d_out;

    // d_out doubles as the 4 MB partial-sum scratch (k_out overwrites it all).
    float* partial = (float*)d_out;
    float* factor  = (float*)d_ws;                  // BATCH*NA floats
    float* gsum    = (float*)d_ws + BATCH * NA;     // BATCH*NA floats

    // gsum must be zero each call (ws is poisoned once, never re-poisoned).
    hipMemsetAsync(gsum, 0, BATCH * NA * sizeof(float), stream);

    k_sums  <<<NBLOCKS, 256, 0, stream>>>(lights, settle, admin, partial, gsum);
    k_reduce<<<BATCH,   512, 0, stream>>>(partial, gsum, census, factor);
    k_out   <<<NBLOCKS, 256, 0, stream>>>(lights, settle, admin, factor, out);
}

// Round 6
// 56.186 us; speedup vs baseline: 10.1304x; 10.1304x over previous
//
#include <hip/hip_runtime.h>

#define BATCH   8
#define HW      (1024 * 1024)
#define NA      512
#define EPSV    1e-8f
#define LAML    0.01f
#define LAMS    0.01f

#define BPB      256                        // blocks per batch
#define NBLOCKS  (BATCH * BPB)              // 2048
#define PIXB     (HW / BPB)                 // 4096 pixels per block
#define UNROLL   4                          // float4 groups per thread

#define NCOPY    16                         // privatized columns, copy = lane&15
#define SCALE    2097152.0f                 // 2^21 fixed-point scale
#define INVSCALE (1.0f / 2097152.0f)

// Pass 1: fixed-point u32 LDS atomics, conflict-bounded lane-column layout.
__global__ __launch_bounds__(256) void k_sums(const float* __restrict__ lights,
                                              const float* __restrict__ settle,
                                              const int*   __restrict__ admin,
                                              float*       __restrict__ partial) {
    __shared__ unsigned int bins[NA * NCOPY];   // 32 KB
    const int tid = threadIdx.x;

    #pragma unroll
    for (int i = tid; i < NA * NCOPY; i += 256) bins[i] = 0u;
    __syncthreads();

    const int b     = blockIdx.x >> 8;      // / BPB
    const int chunk = blockIdx.x & (BPB - 1);
    const long base = (long)b * HW + (long)chunk * PIXB;

    const float4* __restrict__ L4 = (const float4*)(lights + base);
    const float4* __restrict__ S4 = (const float4*)(settle + base);
    const int4*   __restrict__ A4 = (const int4*)(admin + base);

    float4 l[UNROLL], s[UNROLL];
    int4   a[UNROLL];
    #pragma unroll
    for (int u = 0; u < UNROLL; ++u) {
        const int v = tid + u * 256;
        l[u] = L4[v];
        s[u] = S4[v];
        a[u] = A4[v];
    }
    __builtin_amdgcn_sched_barrier(0);      // keep all 12 loads in flight

    const int c = tid & (NCOPY - 1);
    #pragma unroll
    for (int u = 0; u < UNROLL; ++u) {
        atomicAdd(&bins[a[u].x * NCOPY + c],
                  (unsigned)((l[u].x + LAML) * (s[u].x + LAMS) * SCALE + 0.5f));
        atomicAdd(&bins[a[u].y * NCOPY + c],
                  (unsigned)((l[u].y + LAML) * (s[u].y + LAMS) * SCALE + 0.5f));
        atomicAdd(&bins[a[u].z * NCOPY + c],
                  (unsigned)((l[u].z + LAML) * (s[u].z + LAMS) * SCALE + 0.5f));
        atomicAdd(&bins[a[u].w * NCOPY + c],
                  (unsigned)((l[u].w + LAML) * (s[u].w + LAMS) * SCALE + 0.5f));
    }
    __syncthreads();

    float* dst = partial + (long)blockIdx.x * NA;
    for (int i = tid; i < NA; i += 256) {
        unsigned long long t = 0;
        #pragma unroll
        for (int k = 0; k < NCOPY; ++k) t += bins[i * NCOPY + k];
        dst[i] = (float)t * INVSCALE;
    }
}

// Reduce 256 chunk-partials per (batch, admin), emit factor = C/(S+eps).
__global__ __launch_bounds__(512) void k_reduce(const float* __restrict__ partial,
                                                const float* __restrict__ census,
                                                float*       __restrict__ factor) {
    const int b = blockIdx.x;
    const int a = threadIdx.x;              // 512 threads = NA
    const float* p = partial + (long)b * BPB * NA + a;
    float acc = 0.0f;
    #pragma unroll 8
    for (int c = 0; c < BPB; ++c) acc += p[(long)c * NA];
    factor[b * NA + a] = census[a] / (acc + EPSV);
}

// Pass 2: factor table per batch in LDS, recompute score, write out.
__global__ __launch_bounds__(256) void k_out(const float* __restrict__ lights,
                                             const float* __restrict__ settle,
                                             const int*   __restrict__ admin,
                                             const float* __restrict__ factor,
                                             float*       __restrict__ out) {
    __shared__ float lfac[NA];
    const int tid = threadIdx.x;

    const int b     = blockIdx.x >> 8;
    const int chunk = blockIdx.x & (BPB - 1);

    for (int i = tid; i < NA; i += 256)
        lfac[i] = factor[b * NA + i];
    __syncthreads();

    const long base = (long)b * HW + (long)chunk * PIXB;
    const float4* __restrict__ L4 = (const float4*)(lights + base);
    const float4* __restrict__ S4 = (const float4*)(settle + base);
    const int4*   __restrict__ A4 = (const int4*)(admin + base);
    float4*       __restrict__ O4 = (float4*)(out + base);

    #pragma unroll
    for (int u = 0; u < UNROLL; ++u) {
        const int v = tid + u * 256;
        float4 l = L4[v];
        float4 s = S4[v];
        int4   a = A4[v];
        float4 o;
        o.x = (l.x + LAML) * (s.x + LAMS) * lfac[a.x];
        o.y = (l.y + LAML) * (s.y + LAMS) * lfac[a.y];
        o.z = (l.z + LAML) * (s.z + LAMS) * lfac[a.z];
        o.w = (l.w + LAML) * (s.w + LAMS) * lfac[a.w];
        O4[v] = o;
    }
}

extern "C" void kernel_launch(void* const* d_in, const int* in_sizes, int n_in,
                              void* d_out, int out_size, void* d_ws, size_t ws_size,
                              hipStream_t stream) {
    const float* lights = (const float*)d_in[0];
    const float* settle = (const float*)d_in[1];
    const int*   admin  = (const int*)d_in[2];
    const float* census = (const float*)d_in[3];
    float*       out    = (float*)d_out;

    // d_out doubles as the 4 MB partial-sum scratch (k_out overwrites it all).
    float* partial = (float*)d_out;
    float* factor  = (float*)d_ws;          // BATCH*NA floats = 16 KB

    k_sums  <<<NBLOCKS, 256, 0, stream>>>(lights, settle, admin, partial);
    k_reduce<<<BATCH,   512, 0, stream>>>(partial, census, factor);
    k_out   <<<NBLOCKS, 256, 0, stream>>>(lights, settle, admin, factor, out);
}

// Round 8
// 44.497 us; speedup vs baseline: 12.7916x; 1.2627x over previous
//
#include <hip/hip_runtime.h>

#define BATCH   8
#define HW      (1024 * 1024)
#define NA      512
#define EPSV    1e-8f
#define LAML    0.01f
#define LAMS    0.01f

#define BPB      256                        // blocks per batch
#define NBLOCKS  (BATCH * BPB)              // 2048
#define PIXB     (HW / BPB)                 // 4096 pixels per block
#define UNROLL   4                          // float4 groups per thread

#define NCOPY    16                         // privatized bin columns (32 KB LDS)
#define SCALE    4194304.0f                 // 2^22 fixed-point scale
#define INVSCALE (1.0f / 4194304.0f)
// packed word: (admin_id << 23) | q22(score);  score < 1.0201 -> q22 < 2^23

// Pass 1: u32 fixed-point LDS atomics + pack (admin,score) into pck for pass 2.
__global__ __launch_bounds__(256) void k_sums(const float* __restrict__ lights,
                                              const float* __restrict__ settle,
                                              const int*   __restrict__ admin,
                                              float*       __restrict__ partial,
                                              unsigned*    __restrict__ pck) {
    __shared__ unsigned int bins[NA * NCOPY];   // 32 KB
    const int tid = threadIdx.x;

    #pragma unroll
    for (int i = tid; i < NA * NCOPY; i += 256) bins[i] = 0u;
    __syncthreads();

    const long base = (long)blockIdx.x * PIXB;  // == b*HW + chunk*PIXB

    const float4* __restrict__ L4 = (const float4*)(lights + base);
    const float4* __restrict__ S4 = (const float4*)(settle + base);
    const int4*   __restrict__ A4 = (const int4*)(admin + base);
    uint4*        __restrict__ P4 = (uint4*)(pck + base);

    float4 l[UNROLL], s[UNROLL];
    int4   a[UNROLL];
    #pragma unroll
    for (int u = 0; u < UNROLL; ++u) {
        const int v = tid + u * 256;
        l[u] = L4[v];
        s[u] = S4[v];
        a[u] = A4[v];
    }
    __builtin_amdgcn_sched_barrier(0);          // batch all 12 loads

    const int c = tid & (NCOPY - 1);
    #pragma unroll
    for (int u = 0; u < UNROLL; ++u) {
        const unsigned qx = (unsigned)((l[u].x + LAML) * (s[u].x + LAMS) * SCALE + 0.5f);
        const unsigned qy = (unsigned)((l[u].y + LAML) * (s[u].y + LAMS) * SCALE + 0.5f);
        const unsigned qz = (unsigned)((l[u].z + LAML) * (s[u].z + LAMS) * SCALE + 0.5f);
        const unsigned qw = (unsigned)((l[u].w + LAML) * (s[u].w + LAMS) * SCALE + 0.5f);
        atomicAdd(&bins[a[u].x * NCOPY + c], qx);
        atomicAdd(&bins[a[u].y * NCOPY + c], qy);
        atomicAdd(&bins[a[u].z * NCOPY + c], qz);
        atomicAdd(&bins[a[u].w * NCOPY + c], qw);
        uint4 pk;
        pk.x = ((unsigned)a[u].x << 23) | qx;
        pk.y = ((unsigned)a[u].y << 23) | qy;
        pk.z = ((unsigned)a[u].z << 23) | qz;
        pk.w = ((unsigned)a[u].w << 23) | qw;
        P4[tid + u * 256] = pk;
    }
    __syncthreads();

    float* dst = partial + (long)blockIdx.x * NA;
    for (int i = tid; i < NA; i += 256) {
        unsigned long long t = 0;
        #pragma unroll
        for (int k = 0; k < NCOPY; ++k) t += bins[i * NCOPY + k];
        dst[i] = (float)t * INVSCALE;
    }
}

// Reduce 256 chunk-partials per (batch, admin) -> factor = C/(S+eps).
// 64 blocks: (batch, 64-admin slice); 256 thr = 64 admins x 4 chunk-groups.
__global__ __launch_bounds__(256) void k_reduce(const float* __restrict__ partial,
                                                const float* __restrict__ census,
                                                float*       __restrict__ factor) {
    __shared__ float red[256];
    const int b     = blockIdx.x >> 3;
    const int slice = blockIdx.x & 7;
    const int lane  = threadIdx.x & 63;
    const int g     = threadIdx.x >> 6;
    const int a     = slice * 64 + lane;

    const float* p = partial + (long)b * BPB * NA + a;
    float acc = 0.0f;
    #pragma unroll 8
    for (int cc = g * 64; cc < g * 64 + 64; ++cc) acc += p[(long)cc * NA];
    red[threadIdx.x] = acc;
    __syncthreads();
    if (threadIdx.x < 128) red[threadIdx.x] += red[threadIdx.x + 128];
    __syncthreads();
    if (threadIdx.x < 64) {
        float t = red[threadIdx.x] + red[threadIdx.x + 64];
        factor[b * NA + a] = census[a] / (t + EPSV);
    }
}

// Pass 2: read packed (admin,score), gather factor from LDS, write out.
__global__ __launch_bounds__(256) void k_out(const unsigned* __restrict__ pck,
                                             const float*    __restrict__ factor,
                                             float*          __restrict__ out) {
    __shared__ float lfac[NA];
    const int tid = threadIdx.x;
    const int b   = blockIdx.x >> 8;

    for (int i = tid; i < NA; i += 256)
        lfac[i] = factor[b * NA + i];
    __syncthreads();

    const long base = (long)blockIdx.x * PIXB;
    const uint4* __restrict__ P4 = (const uint4*)(pck + base);
    float4*      __restrict__ O4 = (float4*)(out + base);

    #pragma unroll
    for (int u = 0; u < UNROLL; ++u) {
        const int v = tid + u * 256;
        uint4 p = P4[v];
        float4 o;
        o.x = (float)(p.x & 0x7FFFFFu) * INVSCALE * lfac[p.x >> 23];
        o.y = (float)(p.y & 0x7FFFFFu) * INVSCALE * lfac[p.y >> 23];
        o.z = (float)(p.z & 0x7FFFFFu) * INVSCALE * lfac[p.z >> 23];
        o.w = (float)(p.w & 0x7FFFFFu) * INVSCALE * lfac[p.w >> 23];
        O4[v] = o;
    }
}

extern "C" void kernel_launch(void* const* d_in, const int* in_sizes, int n_in,
                              void* d_out, int out_size, void* d_ws, size_t ws_size,
                              hipStream_t stream) {
    const float* lights = (const float*)d_in[0];
    const float* settle = (const float*)d_in[1];
    const int*   admin  = (const int*)d_in[2];
    const float* census = (const float*)d_in[3];
    float*       out    = (float*)d_out;

    float* partial = (float*)d_ws;                        // NBLOCKS*NA = 4 MB
    float* factor  = (float*)d_ws + (long)NBLOCKS * NA;   // BATCH*NA
    unsigned* pck  = (unsigned*)d_out;                    // d_out doubles as packed scratch

    k_sums  <<<NBLOCKS, 256, 0, stream>>>(lights, settle, admin, partial, pck);
    k_reduce<<<64,      256, 0, stream>>>(partial, census, factor);
    k_out   <<<NBLOCKS, 256, 0, stream>>>(pck, factor, out);
}

// Round 9
// 41.846 us; speedup vs baseline: 13.6018x; 1.0633x over previous
//
#include <hip/hip_runtime.h>

#define BATCH   8
#define HW      (1024 * 1024)
#define NA      512
#define EPSV    1e-8f
#define LAML    0.01f
#define LAMS    0.01f

#define BPB      128                        // blocks per batch
#define NBLOCKS  (BATCH * BPB)              // 1024 = 4 blocks/CU
#define PIXB     (HW / BPB)                 // 8192 pixels per block
#define UNROLL   8                          // float4 groups per thread (32 px)

#define NCOPY    16                         // privatized bin columns (32 KB LDS)
#define SCALE    4194304.0f                 // 2^22 fixed-point scale
#define INVSCALE (1.0f / 4194304.0f)
// packed word: (admin_id << 23) | q22(score);  score < 1.0201 -> q22 < 2^23

// Pass 1: u32 fixed-point LDS atomics + pack (admin,score) into pck for pass 2.
__global__ __launch_bounds__(256, 4) void k_sums(const float* __restrict__ lights,
                                                 const float* __restrict__ settle,
                                                 const int*   __restrict__ admin,
                                                 float*       __restrict__ partial,
                                                 unsigned*    __restrict__ pck) {
    __shared__ unsigned int bins[NA * NCOPY];   // 32 KB
    const int tid = threadIdx.x;

    #pragma unroll
    for (int i = tid; i < NA * NCOPY; i += 256) bins[i] = 0u;
    __syncthreads();

    const long base = (long)blockIdx.x * PIXB;

    const float4* __restrict__ L4 = (const float4*)(lights + base);
    const float4* __restrict__ S4 = (const float4*)(settle + base);
    const int4*   __restrict__ A4 = (const int4*)(admin + base);
    uint4*        __restrict__ P4 = (uint4*)(pck + base);

    float4 l[UNROLL], s[UNROLL];
    int4   a[UNROLL];
    #pragma unroll
    for (int u = 0; u < UNROLL; ++u) {
        const int v = tid + u * 256;
        l[u] = L4[v];
        s[u] = S4[v];
        a[u] = A4[v];
    }
    __builtin_amdgcn_sched_barrier(0);          // keep all 24 loads in flight

    const int c = tid & (NCOPY - 1);
    #pragma unroll
    for (int u = 0; u < UNROLL; ++u) {
        const unsigned qx = (unsigned)((l[u].x + LAML) * (s[u].x + LAMS) * SCALE + 0.5f);
        const unsigned qy = (unsigned)((l[u].y + LAML) * (s[u].y + LAMS) * SCALE + 0.5f);
        const unsigned qz = (unsigned)((l[u].z + LAML) * (s[u].z + LAMS) * SCALE + 0.5f);
        const unsigned qw = (unsigned)((l[u].w + LAML) * (s[u].w + LAMS) * SCALE + 0.5f);
        uint4 pk;
        pk.x = ((unsigned)a[u].x << 23) | qx;
        pk.y = ((unsigned)a[u].y << 23) | qy;
        pk.z = ((unsigned)a[u].z << 23) | qz;
        pk.w = ((unsigned)a[u].w << 23) | qw;
        P4[tid + u * 256] = pk;                 // fire-and-forget store
        atomicAdd(&bins[a[u].x * NCOPY + c], qx);
        atomicAdd(&bins[a[u].y * NCOPY + c], qy);
        atomicAdd(&bins[a[u].z * NCOPY + c], qz);
        atomicAdd(&bins[a[u].w * NCOPY + c], qw);
    }
    __syncthreads();

    float* dst = partial + (long)blockIdx.x * NA;
    for (int i = tid; i < NA; i += 256) {
        unsigned long long t = 0;
        #pragma unroll
        for (int k = 0; k < NCOPY; ++k) t += bins[i * NCOPY + k];
        dst[i] = (float)t * INVSCALE;
    }
}

// Reduce 128 chunk-partials per (batch, admin) -> factor = C/(S+eps).
// 64 blocks: (batch, 64-admin slice); 256 thr = 64 admins x 4 chunk-groups.
__global__ __launch_bounds__(256) void k_reduce(const float* __restrict__ partial,
                                                const float* __restrict__ census,
                                                float*       __restrict__ factor) {
    __shared__ float red[256];
    const int b     = blockIdx.x >> 3;
    const int slice = blockIdx.x & 7;
    const int lane  = threadIdx.x & 63;
    const int g     = threadIdx.x >> 6;
    const int a     = slice * 64 + lane;

    const float* p = partial + (long)b * BPB * NA + a;
    float acc = 0.0f;
    #pragma unroll 8
    for (int cc = g * 32; cc < g * 32 + 32; ++cc) acc += p[(long)cc * NA];
    red[threadIdx.x] = acc;
    __syncthreads();
    if (threadIdx.x < 128) red[threadIdx.x] += red[threadIdx.x + 128];
    __syncthreads();
    if (threadIdx.x < 64) {
        float t = red[threadIdx.x] + red[threadIdx.x + 64];
        factor[b * NA + a] = census[a] / (t + EPSV);
    }
}

// Pass 2: read packed (admin,score), gather factor from LDS, write out.
__global__ __launch_bounds__(256, 4) void k_out(const unsigned* __restrict__ pck,
                                                const float*    __restrict__ factor,
                                                float*          __restrict__ out) {
    __shared__ float lfac[NA];
    const int tid = threadIdx.x;
    const int b   = blockIdx.x >> 7;            // / BPB

    for (int i = tid; i < NA; i += 256)
        lfac[i] = factor[b * NA + i];
    __syncthreads();

    const long base = (long)blockIdx.x * PIXB;
    const uint4* __restrict__ P4 = (const uint4*)(pck + base);
    float4*      __restrict__ O4 = (float4*)(out + base);

    uint4 p[UNROLL];
    #pragma unroll
    for (int u = 0; u < UNROLL; ++u) p[u] = P4[tid + u * 256];
    __builtin_amdgcn_sched_barrier(0);          // 8 loads in flight

    #pragma unroll
    for (int u = 0; u < UNROLL; ++u) {
        float4 o;
        o.x = (float)(p[u].x & 0x7FFFFFu) * INVSCALE * lfac[p[u].x >> 23];
        o.y = (float)(p[u].y & 0x7FFFFFu) * INVSCALE * lfac[p[u].y >> 23];
        o.z = (float)(p[u].z & 0x7FFFFFu) * INVSCALE * lfac[p[u].z >> 23];
        o.w = (float)(p[u].w & 0x7FFFFFu) * INVSCALE * lfac[p[u].w >> 23];
        O4[tid + u * 256] = o;
    }
}

extern "C" void kernel_launch(void* const* d_in, const int* in_sizes, int n_in,
                              void* d_out, int out_size, void* d_ws, size_t ws_size,
                              hipStream_t stream) {
    const float* lights = (const float*)d_in[0];
    const float* settle = (const float*)d_in[1];
    const int*   admin  = (const int*)d_in[2];
    const float* census = (const float*)d_in[3];
    float*       out    = (float*)d_out;

    float* partial = (float*)d_ws;                        // NBLOCKS*NA = 2 MB
    float* factor  = (float*)d_ws + (long)NBLOCKS * NA;   // BATCH*NA
    unsigned* pck  = (unsigned*)d_out;                    // d_out doubles as packed scratch

    k_sums  <<<NBLOCKS, 256, 0, stream>>>(lights, settle, admin, partial, pck);
    k_reduce<<<64,      256, 0, stream>>>(partial, census, factor);
    k_out   <<<NBLOCKS, 256, 0, stream>>>(pck, factor, out);
}